// Round 2
// baseline (550.135 us; speedup 1.0000x reference)
//
#include <hip/hip_runtime.h>
#include <math.h>

// ---------------------------------------------------------------------------
// FFT_MLP_KAN: FFT features -> 4 fused KAN layers -> 3 folded MLP heads.
// All fp32. B = 8192, layer dims 504->80->160->80->40 -> 3.
// ---------------------------------------------------------------------------

__device__ __forceinline__ float silu_f(float x) {
    return x / (1.f + __expf(-x));
}

// ---------------------------------------------------------------------------
// FFT feature kernel: x (B,64,14) viewed as rows of 64 samples per (b,c) pair
// (reshape semantics: pair p=b*14+c owns x[p*64 .. p*64+63]).
// Output F0[p*36 + q] = [abs(prev9), angle(cur9), abs(cur9), angle(cur9)].
// ---------------------------------------------------------------------------
__global__ __launch_bounds__(128) void fft_kernel(const float* __restrict__ x,
                                                  float* __restrict__ F0, int P) {
    __shared__ float xs[128 * 65];          // 128 rows of 64, pad 65 (bank-safe)
    __shared__ float twc[288], tws[288];    // cos / sin(-2*pi*k*n/32), k<9, n<32
    int tid = threadIdx.x;
    for (int t = tid; t < 288; t += 128) {
        int k = t >> 5, n = t & 31;
        int m = (k * n) & 31;               // periodic reduction, keeps arg small
        float ang = -0.19634954084936207f * (float)m;   // -2*pi/32 * m
        float s, c;
        sincosf(ang, &s, &c);
        twc[t] = c; tws[t] = s;             // tws = sin(-theta) = -sin(theta)
    }
    int p0 = blockIdx.x * 128;
    for (int idx = tid; idx < 128 * 64; idx += 128) {
        int g = p0 * 64 + idx;
        float v = (g < P * 64) ? x[g] : 0.f;
        xs[(idx >> 6) * 65 + (idx & 63)] = v;
    }
    __syncthreads();
    int p = p0 + tid;
    if (p >= P) return;
    const float* row = &xs[tid * 65];
    float r[64];
#pragma unroll
    for (int n = 0; n < 64; ++n) r[n] = row[n];
    float outv[36];
#pragma unroll
    for (int k = 0; k < 9; ++k) {
        float rp = 0.f, ip = 0.f, rc = 0.f, ic = 0.f;
#pragma unroll
        for (int n = 0; n < 32; ++n) {
            float c = twc[k * 32 + n], s = tws[k * 32 + n];
            // X[k] = sum x[n] * exp(-i*theta): real += x*cos, imag += x*sin(-theta)
            rp = fmaf(r[n], c, rp);
            ip = fmaf(r[n], s, ip);
            rc = fmaf(r[n + 32], c, rc);
            ic = fmaf(r[n + 32], s, ic);
        }
        float ap = sqrtf(fmaf(rp, rp, ip * ip));
        float ac = sqrtf(fmaf(rc, rc, ic * ic));
        float gc = atan2f(ic, rc);          // NOTE: cur phase used twice (faithful)
        outv[k] = ap; outv[9 + k] = gc; outv[18 + k] = ac; outv[27 + k] = gc;
    }
    float* dst = &F0[(size_t)p * 36];
#pragma unroll
    for (int q = 0; q < 36; ++q) dst[q] = outv[q];
}

// ---------------------------------------------------------------------------
// Fused-weight prep: Wf[(i*14 + c)*OUT + o]; c=0 -> base_w, c>=1 -> spline*scaler
// ---------------------------------------------------------------------------
__global__ void prep_kan_kernel(float* __restrict__ Wf, const float* __restrict__ base_w,
                                const float* __restrict__ spline_w,
                                const float* __restrict__ scaler, int IN, int OUT) {
    int id = blockIdx.x * 256 + threadIdx.x;
    int total = IN * 14 * OUT;
    if (id >= total) return;
    int o = id % OUT;
    int rem = id / OUT;
    int c = rem % 14;
    int i = rem / 14;
    float v;
    if (c == 0) v = base_w[o * IN + i];
    else        v = spline_w[((size_t)o * IN + i) * 13 + (c - 1)] * scaler[o * IN + i];
    Wf[id] = v;
}

// Heads fold: LeakyReLU(True) == identity, so y2 = h @ (W2@W1)^T + (W2@b1 + b2).
__global__ void prep_heads_kernel(float* __restrict__ W21, float* __restrict__ b21,
                                  const float* __restrict__ W1, const float* __restrict__ b1,
                                  const float* __restrict__ W2, const float* __restrict__ b2) {
    int id = blockIdx.x * 256 + threadIdx.x;
    if (id < 3 * 20 * 40) {
        int k = id % 40; int rem = id / 40; int j = rem % 20; int h = rem / 20;
        float a = 0.f;
        for (int m = 0; m < 40; ++m)
            a = fmaf(W2[(h * 20 + j) * 40 + m], W1[(h * 40 + m) * 40 + k], a);
        W21[id] = a;
    } else if (id < 3 * 20 * 40 + 60) {
        int t = id - 2400; int j = t % 20; int h = t / 20;
        float a = b2[h * 20 + j];
        for (int m = 0; m < 40; ++m)
            a = fmaf(W2[(h * 20 + j) * 40 + m], b1[h * 40 + m], a);
        b21[t] = a;
    }
}

// ---------------------------------------------------------------------------
// Fused KAN layer: Y[b,o] = sum_i silu(x)*Wb + sum_c B_c(x)*Ws.
// One wave per block, BM=32 rows, split-K across blockIdx.y into partials Yp.
// Features (14 per (b,i)) computed via closed-form uniform cubic B-spline.
// ---------------------------------------------------------------------------
template <int OUT, int COLS_T, int NR, int MR>
__global__ __launch_bounds__(64) void kan_kernel(const float* __restrict__ X, int IN,
                                                 const float* __restrict__ Wf,
                                                 float* __restrict__ Yp, int B, int kcount) {
    constexpr int BM = 32;
    constexpr int ROWS_T = 64 / COLS_T;
    static_assert(ROWS_T * MR == BM, "tile mismatch");
    static_assert(COLS_T * NR == OUT, "col mismatch");
    __shared__ float Fs[2][BM][15];         // 14 features + pad (conflict-free)
    __shared__ float Ws[2 * 14 * OUT];

    int tid = threadIdx.x;
    int ct = tid % COLS_T, rt = tid / COLS_T;
    int b0 = blockIdx.x * BM;
    int s = blockIdx.y;
    int ibase = s * kcount;
    int kc_local = min(kcount, IN - ibase);

    float acc[MR][NR];
#pragma unroll
    for (int m = 0; m < MR; ++m)
#pragma unroll
        for (int n = 0; n < NR; ++n) acc[m][n] = 0.f;

    for (int i0 = 0; i0 < kc_local; i0 += 2) {
        int valid = (kc_local - i0 >= 2) ? 2 : 1;
        // stage weights (contiguous, coalesced)
        const float* wsrc = Wf + (size_t)(ibase + i0) * 14 * OUT;
        int wcount = valid * 14 * OUT;
        for (int t = tid; t < wcount; t += 64) Ws[t] = wsrc[t];
        // compute features for 2*32 cells (1 per thread)
        {
            int k = tid >> 5, rr = tid & 31;
            float* f = &Fs[k][rr][0];
#pragma unroll
            for (int c = 0; c < 14; ++c) f[c] = 0.f;
            if (k < valid) {
                float xv = X[(size_t)(b0 + rr) * IN + (ibase + i0 + k)];
                f[0] = silu_f(xv);
                float t10 = (xv + 0.3f) * 10.f;
                if (t10 >= 0.f && t10 < 16.f) {
                    int j = (int)t10;           // interval: x in [g[j], g[j+1])
                    float u = t10 - (float)j;
                    float u2 = u * u, u3 = u2 * u;
                    float v = 1.f - u;
                    float B0 = v * v * v * (1.f / 6.f);
                    float B1 = (3.f * u3 - 6.f * u2 + 4.f) * (1.f / 6.f);
                    float B2 = (-3.f * u3 + 3.f * u2 + 3.f * u + 1.f) * (1.f / 6.f);
                    float B3 = u3 * (1.f / 6.f);
                    int base = j - 3;           // bases j-3..j, clipped to [0,12]
                    if (base >= 0 && base <= 12) f[1 + base] = B0;
                    if (base + 1 >= 0 && base + 1 <= 12) f[2 + base] = B1;
                    if (base + 2 >= 0 && base + 2 <= 12) f[3 + base] = B2;
                    if (base + 3 >= 0 && base + 3 <= 12) f[4 + base] = B3;
                }
            }
        }
        __syncthreads();
#pragma unroll
        for (int k = 0; k < 2; ++k) {
#pragma unroll
            for (int c = 0; c < 14; ++c) {
                float w[NR];
#pragma unroll
                for (int n = 0; n < NR; ++n) w[n] = Ws[(k * 14 + c) * OUT + ct * NR + n];
#pragma unroll
                for (int m = 0; m < MR; ++m) {
                    float fm = Fs[k][rt * MR + m][c];
#pragma unroll
                    for (int n = 0; n < NR; ++n) acc[m][n] = fmaf(fm, w[n], acc[m][n]);
                }
            }
        }
        __syncthreads();
    }
    float* ydst = Yp + (size_t)s * B * OUT;
#pragma unroll
    for (int m = 0; m < MR; ++m)
#pragma unroll
        for (int n = 0; n < NR; ++n)
            ydst[(size_t)(b0 + rt * MR + m) * OUT + ct * NR + n] = acc[m][n];
}

__global__ void reduce_kernel(float* __restrict__ Y, const float* __restrict__ Yp,
                              int N, int KS) {
    int t = blockIdx.x * 256 + threadIdx.x;
    if (t >= N) return;
    float a = 0.f;
    for (int s = 0; s < KS; ++s) a += Yp[(size_t)s * N + t];
    Y[t] = a;
}

// ---------------------------------------------------------------------------
// Heads: one thread per (b, head). y2 = h@W21^T + b21; LeakyReLU(0.05); dot W3;
// sigmoid. out[b*3+h].
// ---------------------------------------------------------------------------
__global__ __launch_bounds__(256) void heads_kernel(const float* __restrict__ h4,
                                                    const float* __restrict__ W21,
                                                    const float* __restrict__ b21,
                                                    const float* __restrict__ W3,
                                                    const float* __restrict__ b3,
                                                    float* __restrict__ out, int B) {
    __shared__ float w21s[2400], b21s[60], w3s[60], b3s[3];
    int tid = threadIdx.x;
    for (int t = tid; t < 2400; t += 256) w21s[t] = W21[t];
    if (tid < 60) { b21s[tid] = b21[tid]; w3s[tid] = W3[tid]; }
    if (tid < 3) b3s[tid] = b3[tid];
    __syncthreads();
    int id = blockIdx.x * 256 + tid;
    if (id >= B * 3) return;
    int b = id / 3, h = id % 3;
    const float* hr = &h4[(size_t)b * 40];
    float hv[40];
#pragma unroll
    for (int m = 0; m < 40; ++m) hv[m] = hr[m];
    float z = b3s[h];
#pragma unroll
    for (int j = 0; j < 20; ++j) {
        float y = b21s[h * 20 + j];
        const float* wr = &w21s[(h * 20 + j) * 40];
#pragma unroll
        for (int m = 0; m < 40; ++m) y = fmaf(wr[m], hv[m], y);
        y = (y >= 0.f) ? y : 0.05f * y;
        z = fmaf(w3s[h * 20 + j], y, z);
    }
    out[id] = 1.f / (1.f + __expf(-z));
}

// ---------------------------------------------------------------------------
extern "C" void kernel_launch(void* const* d_in, const int* in_sizes, int n_in,
                              void* d_out, int out_size, void* d_ws, size_t ws_size,
                              hipStream_t stream) {
    const float* x   = (const float*)d_in[0];
    const float* k1b = (const float*)d_in[1];
    const float* k1s = (const float*)d_in[2];
    const float* k1c = (const float*)d_in[3];
    const float* k2b = (const float*)d_in[4];
    const float* k2s = (const float*)d_in[5];
    const float* k2c = (const float*)d_in[6];
    const float* k3b = (const float*)d_in[7];
    const float* k3s = (const float*)d_in[8];
    const float* k3c = (const float*)d_in[9];
    const float* k4b = (const float*)d_in[10];
    const float* k4s = (const float*)d_in[11];
    const float* k4c = (const float*)d_in[12];
    const float* hW1 = (const float*)d_in[13];
    const float* hb1 = (const float*)d_in[14];
    const float* hW2 = (const float*)d_in[15];
    const float* hb2 = (const float*)d_in[16];
    const float* hW3 = (const float*)d_in[17];
    const float* hb3 = (const float*)d_in[18];
    float* out = (float*)d_out;

    int B = in_sizes[0] / (64 * 14);
    int P = B * 14;

    float* ws = (float*)d_ws;
    size_t off = 0;
    float* F0  = ws + off; off += (size_t)B * 504;
    float* h1  = ws + off; off += (size_t)B * 80;
    float* h2  = ws + off; off += (size_t)B * 160;
    float* h3  = ws + off; off += (size_t)B * 80;
    float* h4  = ws + off; off += (size_t)B * 40;
    float* Wf1 = ws + off; off += 504 * 14 * 80;
    float* Wf2 = ws + off; off += 80 * 14 * 160;
    float* Wf3 = ws + off; off += 160 * 14 * 80;
    float* Wf4 = ws + off; off += 80 * 14 * 40;
    float* W21 = ws + off; off += 2400;
    float* b21 = ws + off; off += 60;
    float* Yp  = ws + off; off += (size_t)B * 640;   // max split-K partials

    // ---- weight prep (cheap, every launch: no persistent state allowed) ----
    prep_kan_kernel<<<(504 * 14 * 80 + 255) / 256, 256, 0, stream>>>(Wf1, k1b, k1s, k1c, 504, 80);
    prep_kan_kernel<<<(80 * 14 * 160 + 255) / 256, 256, 0, stream>>>(Wf2, k2b, k2s, k2c, 80, 160);
    prep_kan_kernel<<<(160 * 14 * 80 + 255) / 256, 256, 0, stream>>>(Wf3, k3b, k3s, k3c, 160, 80);
    prep_kan_kernel<<<(80 * 14 * 40 + 255) / 256, 256, 0, stream>>>(Wf4, k4b, k4s, k4c, 80, 40);
    prep_heads_kernel<<<(2460 + 255) / 256, 256, 0, stream>>>(W21, b21, hW1, hb1, hW2, hb2);

    // ---- FFT features ----
    fft_kernel<<<(P + 127) / 128, 128, 0, stream>>>(x, F0, P);

    // ---- KAN layers (split-K into Yp, then reduce) ----
    // L1: 504 -> 80, KS=8 (kcount=63, odd tail handled)
    kan_kernel<80, 8, 10, 4><<<dim3(B / 32, 8), 64, 0, stream>>>(F0, 504, Wf1, Yp, B, 63);
    reduce_kernel<<<((B * 80) + 255) / 256, 256, 0, stream>>>(h1, Yp, B * 80, 8);
    // L2: 80 -> 160, KS=4
    kan_kernel<160, 16, 10, 8><<<dim3(B / 32, 4), 64, 0, stream>>>(h1, 80, Wf2, Yp, B, 20);
    reduce_kernel<<<((B * 160) + 255) / 256, 256, 0, stream>>>(h2, Yp, B * 160, 4);
    // L3: 160 -> 80, KS=4
    kan_kernel<80, 8, 10, 4><<<dim3(B / 32, 4), 64, 0, stream>>>(h2, 160, Wf3, Yp, B, 40);
    reduce_kernel<<<((B * 80) + 255) / 256, 256, 0, stream>>>(h3, Yp, B * 80, 4);
    // L4: 80 -> 40, KS=4
    kan_kernel<40, 8, 5, 4><<<dim3(B / 32, 4), 64, 0, stream>>>(h3, 80, Wf4, Yp, B, 20);
    reduce_kernel<<<((B * 40) + 255) / 256, 256, 0, stream>>>(h4, Yp, B * 40, 4);

    // ---- heads ----
    heads_kernel<<<(B * 3 + 255) / 256, 256, 0, stream>>>(h4, W21, b21, hW3, hb3, out, B);

    (void)n_in; (void)out_size; (void)ws_size;
}